// Round 1
// baseline (662.584 us; speedup 1.0000x reference)
//
#include <hip/hip_runtime.h>
#include <hip/hip_bf16.h>

#define BSZ   4
#define NSEQ  2048
#define DIMM  1024
#define NHEAD 16
#define HD    64
#define N3    (3*DIMM)
#define MTOK  (BSZ*NSEQ)      // 8192
#define SCALE 0.125f          // 64^-0.5

typedef __attribute__((ext_vector_type(8))) short   short8;
typedef __attribute__((ext_vector_type(4))) short   short4v;
typedef __attribute__((ext_vector_type(8))) __bf16  bf16x8;
typedef __attribute__((ext_vector_type(4))) float   f32x4;

__device__ inline short f2bf(float f) {
    unsigned u = __builtin_bit_cast(unsigned, f);
    u += 0x7fffu + ((u >> 16) & 1u);          // RNE
    return (short)(u >> 16);
}

__device__ inline bf16x8 lds_frag(const short* p) {
    return __builtin_bit_cast(bf16x8, *(const short8*)p);
}

// ---------------------------------------------------------------------------
// GEMM1: qkv = x[8192,1024] @ w_qkv[1024,3072], scatter to q/k (row) + v (T)
// ---------------------------------------------------------------------------
__global__ __launch_bounds__(256, 2)
void gemm_qkv(const float* __restrict__ x, const float* __restrict__ w,
              short* __restrict__ qo, short* __restrict__ ko,
              short* __restrict__ vo)
{
    __shared__ short As[128][40];   // [m][k], pad 40 (80B = 5x16B)
    __shared__ short Bs[128][40];   // [n][k] (B transposed)
    const int tid  = threadIdx.x;
    const int wave = tid >> 6, lane = tid & 63;
    const int quad = lane >> 4, l16 = lane & 15;
    const int row0 = blockIdx.x * 128, col0 = blockIdx.y * 128;
    const int wm = (wave >> 1) * 64, wn = (wave & 1) * 64;

    f32x4 acc[4][4] = {};

    for (int k0 = 0; k0 < DIMM; k0 += 32) {
        // stage A 128x32 fp32 -> bf16
        #pragma unroll
        for (int i = 0; i < 4; ++i) {
            int f = tid + i * 256;
            int r = f >> 3, kg = f & 7;
            float4 v4 = *(const float4*)(x + (size_t)(row0 + r) * DIMM + k0 + kg * 4);
            short4v s = { f2bf(v4.x), f2bf(v4.y), f2bf(v4.z), f2bf(v4.w) };
            *(short4v*)&As[r][kg * 4] = s;
        }
        // stage B 32x128 fp32 -> bf16 transposed into Bs[n][k]
        #pragma unroll
        for (int i = 0; i < 4; ++i) {
            int f = tid + i * 256;
            int kr = f >> 5, ng = (f & 31) * 4;
            float4 v4 = *(const float4*)(w + (size_t)(k0 + kr) * N3 + col0 + ng);
            Bs[ng + 0][kr] = f2bf(v4.x);
            Bs[ng + 1][kr] = f2bf(v4.y);
            Bs[ng + 2][kr] = f2bf(v4.z);
            Bs[ng + 3][kr] = f2bf(v4.w);
        }
        __syncthreads();
        bf16x8 a[4], b[4];
        #pragma unroll
        for (int mt = 0; mt < 4; ++mt) a[mt] = lds_frag(&As[wm + mt * 16 + l16][quad * 8]);
        #pragma unroll
        for (int nt = 0; nt < 4; ++nt) b[nt] = lds_frag(&Bs[wn + nt * 16 + l16][quad * 8]);
        #pragma unroll
        for (int mt = 0; mt < 4; ++mt)
            #pragma unroll
            for (int nt = 0; nt < 4; ++nt)
                acc[mt][nt] = __builtin_amdgcn_mfma_f32_16x16x32_bf16(a[mt], b[nt], acc[mt][nt], 0, 0, 0);
        __syncthreads();
    }

    // epilogue: scatter to q/k [BH][N][64], v [BH][64][N]
    #pragma unroll
    for (int mt = 0; mt < 4; ++mt) {
        #pragma unroll
        for (int nt = 0; nt < 4; ++nt) {
            int gcol  = col0 + wn + nt * 16 + l16;
            int which = gcol >> 10;          // 0=q 1=k 2=v
            int cc    = gcol & 1023;
            int h     = cc >> 6, d = cc & 63;
            int growb = row0 + wm + mt * 16 + quad * 4;   // rows growb..growb+3
            int b_    = growb >> 11;
            int n_    = growb & 2047;
            int bh    = b_ * NHEAD + h;
            if (which == 2) {
                // consecutive rows n -> consecutive addresses in vT
                short4v s = { f2bf(acc[mt][nt][0]), f2bf(acc[mt][nt][1]),
                              f2bf(acc[mt][nt][2]), f2bf(acc[mt][nt][3]) };
                *(short4v*)(vo + ((size_t)bh * HD + d) * NSEQ + n_) = s;
            } else {
                short* dst = (which == 0 ? qo : ko);
                #pragma unroll
                for (int r = 0; r < 4; ++r)
                    dst[((size_t)bh * NSEQ + n_ + r) * HD + d] = f2bf(acc[mt][nt][r]);
            }
        }
    }
}

// ---------------------------------------------------------------------------
// Flash attention: per block 64 Q-rows x one (b,h); KV tiles of 128
// q,k: [BH][N][64] bf16; vt: [BH][64][N] bf16; o: [B][N][H*64] bf16
// ---------------------------------------------------------------------------
__global__ __launch_bounds__(256, 2)
void attn(const short* __restrict__ q, const short* __restrict__ k,
          const short* __restrict__ vt, short* __restrict__ o)
{
    __shared__ short Qs[64][72];     // [qrow][d]   (144B = 9x16B stride)
    __shared__ short Ks[128][72];    // [kvrow][d]
    __shared__ short Vts[64][136];   // [d][kv]     (272B = 17x16B stride)
    __shared__ short Ps[64][136];    // [qrow][kv]

    const int tid  = threadIdx.x;
    const int wave = tid >> 6, lane = tid & 63;
    const int quad = lane >> 4, l16 = lane & 15;
    const int bh   = blockIdx.y;
    const int q0   = blockIdx.x * 64;
    const size_t qkbase = (size_t)bh * NSEQ * HD;
    const size_t vbase  = (size_t)bh * HD * NSEQ;

    // stage Q tile 64x64
    #pragma unroll
    for (int i = 0; i < 2; ++i) {
        int f = tid + i * 256;
        int r = f >> 3, dg = (f & 7) * 8;
        *(short8*)&Qs[r][dg] = *(const short8*)(q + qkbase + (size_t)(q0 + r) * HD + dg);
    }
    __syncthreads();

    bf16x8 qf[2];
    #pragma unroll
    for (int ks = 0; ks < 2; ++ks)
        qf[ks] = lds_frag(&Qs[wave * 16 + l16][ks * 32 + quad * 8]);

    f32x4 oacc[4] = {};
    float mst[4], lst[4];
    #pragma unroll
    for (int r = 0; r < 4; ++r) { mst[r] = -1e30f; lst[r] = 0.f; }

    for (int kv0 = 0; kv0 < NSEQ; kv0 += 128) {
        // stage K tile 128x64
        #pragma unroll
        for (int i = 0; i < 4; ++i) {
            int f = tid + i * 256;
            int r = f >> 3, dg = (f & 7) * 8;
            *(short8*)&Ks[r][dg] = *(const short8*)(k + qkbase + (size_t)(kv0 + r) * HD + dg);
        }
        // stage Vt tile 64x128
        #pragma unroll
        for (int i = 0; i < 4; ++i) {
            int f = tid + i * 256;
            int r = f >> 4, jg = (f & 15) * 8;
            *(short8*)&Vts[r][jg] = *(const short8*)(vt + vbase + (size_t)r * NSEQ + kv0 + jg);
        }
        __syncthreads();

        // S = Q K^T : wave's 16 rows x 128 cols
        f32x4 sacc[8] = {};
        #pragma unroll
        for (int ks = 0; ks < 2; ++ks) {
            #pragma unroll
            for (int nt = 0; nt < 8; ++nt) {
                bf16x8 kf = lds_frag(&Ks[nt * 16 + l16][ks * 32 + quad * 8]);
                sacc[nt] = __builtin_amdgcn_mfma_f32_16x16x32_bf16(qf[ks], kf, sacc[nt], 0, 0, 0);
            }
        }

        // online softmax, per owned row (quad*4 + r)
        #pragma unroll
        for (int r = 0; r < 4; ++r) {
            float rmax = -1e30f;
            #pragma unroll
            for (int nt = 0; nt < 8; ++nt) rmax = fmaxf(rmax, sacc[nt][r]);
            rmax *= SCALE;
            #pragma unroll
            for (int off = 1; off < 16; off <<= 1)
                rmax = fmaxf(rmax, __shfl_xor(rmax, off));
            float mnew  = fmaxf(mst[r], rmax);
            float alpha = __expf(mst[r] - mnew);
            float rsum  = 0.f;
            int prow = wave * 16 + quad * 4 + r;
            #pragma unroll
            for (int nt = 0; nt < 8; ++nt) {
                float p = __expf(sacc[nt][r] * SCALE - mnew);
                Ps[prow][nt * 16 + l16] = f2bf(p);
                rsum += p;
            }
            #pragma unroll
            for (int off = 1; off < 16; off <<= 1)
                rsum += __shfl_xor(rsum, off);
            lst[r] = lst[r] * alpha + rsum;
            mst[r] = mnew;
            #pragma unroll
            for (int ot = 0; ot < 4; ++ot) oacc[ot][r] *= alpha;
        }

        // O += P V  (A = Ps rows of this wave, B = Vt fragments)
        #pragma unroll
        for (int ks = 0; ks < 4; ++ks) {
            bf16x8 pf = lds_frag(&Ps[wave * 16 + l16][ks * 32 + quad * 8]);
            #pragma unroll
            for (int ot = 0; ot < 4; ++ot) {
                bf16x8 vf = lds_frag(&Vts[ot * 16 + l16][ks * 32 + quad * 8]);
                oacc[ot] = __builtin_amdgcn_mfma_f32_16x16x32_bf16(pf, vf, oacc[ot], 0, 0, 0);
            }
        }
        __syncthreads();
    }

    // epilogue: normalize, write o[B][N][H*64]
    const int b_ = bh >> 4, h = bh & 15;
    #pragma unroll
    for (int ot = 0; ot < 4; ++ot) {
        #pragma unroll
        for (int r = 0; r < 4; ++r) {
            int row = q0 + wave * 16 + quad * 4 + r;
            int d   = ot * 16 + l16;
            float val = oacc[ot][r] / lst[r];
            o[((size_t)b_ * NSEQ + row) * DIMM + h * HD + d] = f2bf(val);
        }
    }
}

// ---------------------------------------------------------------------------
// GEMM2: out = o[8192,1024](bf16) @ w_out[1024,1024](fp32->bf16) + b_out
// ---------------------------------------------------------------------------
__global__ __launch_bounds__(256, 2)
void gemm_out(const short* __restrict__ ob, const float* __restrict__ w,
              const float* __restrict__ bias, float* __restrict__ out)
{
    __shared__ short As[128][40];
    __shared__ short Bs[128][40];
    const int tid  = threadIdx.x;
    const int wave = tid >> 6, lane = tid & 63;
    const int quad = lane >> 4, l16 = lane & 15;
    const int row0 = blockIdx.x * 128, col0 = blockIdx.y * 128;
    const int wm = (wave >> 1) * 64, wn = (wave & 1) * 64;

    f32x4 acc[4][4] = {};

    for (int k0 = 0; k0 < DIMM; k0 += 32) {
        // stage A (already bf16): 128x32 = 512 chunks of 8
        #pragma unroll
        for (int i = 0; i < 2; ++i) {
            int f = tid + i * 256;
            int r = f >> 2, kg = f & 3;
            *(short8*)&As[r][kg * 8] =
                *(const short8*)(ob + (size_t)(row0 + r) * DIMM + k0 + kg * 8);
        }
        // stage B 32x128 fp32 -> bf16 transposed
        #pragma unroll
        for (int i = 0; i < 4; ++i) {
            int f = tid + i * 256;
            int kr = f >> 5, ng = (f & 31) * 4;
            float4 v4 = *(const float4*)(w + (size_t)(k0 + kr) * DIMM + col0 + ng);
            Bs[ng + 0][kr] = f2bf(v4.x);
            Bs[ng + 1][kr] = f2bf(v4.y);
            Bs[ng + 2][kr] = f2bf(v4.z);
            Bs[ng + 3][kr] = f2bf(v4.w);
        }
        __syncthreads();
        bf16x8 a[4], b[4];
        #pragma unroll
        for (int mt = 0; mt < 4; ++mt) a[mt] = lds_frag(&As[wm + mt * 16 + l16][quad * 8]);
        #pragma unroll
        for (int nt = 0; nt < 4; ++nt) b[nt] = lds_frag(&Bs[wn + nt * 16 + l16][quad * 8]);
        #pragma unroll
        for (int mt = 0; mt < 4; ++mt)
            #pragma unroll
            for (int nt = 0; nt < 4; ++nt)
                acc[mt][nt] = __builtin_amdgcn_mfma_f32_16x16x32_bf16(a[mt], b[nt], acc[mt][nt], 0, 0, 0);
        __syncthreads();
    }

    #pragma unroll
    for (int mt = 0; mt < 4; ++mt) {
        #pragma unroll
        for (int nt = 0; nt < 4; ++nt) {
            int gcol = col0 + wn + nt * 16 + l16;
            float bb = bias[gcol];
            #pragma unroll
            for (int r = 0; r < 4; ++r) {
                int grow = row0 + wm + mt * 16 + quad * 4 + r;
                out[(size_t)grow * DIMM + gcol] = acc[mt][nt][r] + bb;
            }
        }
    }
}

// ---------------------------------------------------------------------------
extern "C" void kernel_launch(void* const* d_in, const int* in_sizes, int n_in,
                              void* d_out, int out_size, void* d_ws, size_t ws_size,
                              hipStream_t stream)
{
    const float* x     = (const float*)d_in[0];
    const float* w_qkv = (const float*)d_in[1];
    const float* w_out = (const float*)d_in[2];
    const float* b_out = (const float*)d_in[3];
    float* out = (float*)d_out;

    const size_t per = (size_t)BSZ * NHEAD * NSEQ * HD;  // 8.39M elems
    short* q  = (short*)d_ws;
    short* kk = q  + per;
    short* v  = kk + per;
    short* ob = v  + per;   // o in [B][N][H*64] layout

    gemm_qkv<<<dim3(MTOK / 128, N3 / 128), 256, 0, stream>>>(x, w_qkv, q, kk, v);
    attn<<<dim3(NSEQ / 64, BSZ * NHEAD), 256, 0, stream>>>(q, kk, v, ob);
    gemm_out<<<dim3(MTOK / 128, DIMM / 128), 256, 0, stream>>>(ob, w_out, b_out, out);
}

// Round 2
// 398.288 us; speedup vs baseline: 1.6636x; 1.6636x over previous
//
#include <hip/hip_runtime.h>
#include <hip/hip_bf16.h>

#define BSZ   4
#define NSEQ  2048
#define DIMM  1024
#define NHEAD 16
#define HD    64
#define N3    (3*DIMM)
#define MTOK  (BSZ*NSEQ)      // 8192
#define SCALE 0.125f          // 64^-0.5

typedef __attribute__((ext_vector_type(8))) short   short8;
typedef __attribute__((ext_vector_type(4))) short   short4v;
typedef __attribute__((ext_vector_type(8))) __bf16  bf16x8;
typedef __attribute__((ext_vector_type(4))) float   f32x4;

__device__ inline short f2bf(float f) {
    unsigned u = __builtin_bit_cast(unsigned, f);
    u += 0x7fffu + ((u >> 16) & 1u);          // RNE
    return (short)(u >> 16);
}

__device__ inline bf16x8 lds_frag(const short* p) {
    return __builtin_bit_cast(bf16x8, *(const short8*)p);
}

__device__ inline void gld_lds16(const short* g, short* l) {
    __builtin_amdgcn_global_load_lds(
        (const __attribute__((address_space(1))) void*)g,
        (__attribute__((address_space(3))) void*)l, 16, 0, 0);
}

// ---------------------------------------------------------------------------
// Prepass 1: fp32 -> bf16 straight copy (8 elems/thread)
// ---------------------------------------------------------------------------
__global__ __launch_bounds__(256)
void cvt_bf16(const float* __restrict__ src, short* __restrict__ dst, int n8)
{
    int i = blockIdx.x * 256 + threadIdx.x;
    if (i >= n8) return;
    float4 v0 = ((const float4*)src)[i * 2];
    float4 v1 = ((const float4*)src)[i * 2 + 1];
    short8 s = { f2bf(v0.x), f2bf(v0.y), f2bf(v0.z), f2bf(v0.w),
                 f2bf(v1.x), f2bf(v1.y), f2bf(v1.z), f2bf(v1.w) };
    ((short8*)dst)[i] = s;
}

// ---------------------------------------------------------------------------
// Prepass 2: transpose src[K][N] fp32 -> dst[N][K] bf16   (block 32x8)
// ---------------------------------------------------------------------------
__global__ __launch_bounds__(256)
void transpose_bf16(const float* __restrict__ src, short* __restrict__ dst,
                    int K, int N)
{
    __shared__ float tile[32][33];
    const int n0 = blockIdx.x * 32, k0 = blockIdx.y * 32;
    const int tx = threadIdx.x, ty = threadIdx.y;
    #pragma unroll
    for (int i = 0; i < 4; ++i)
        tile[ty + i * 8][tx] = src[(size_t)(k0 + ty + i * 8) * N + n0 + tx];
    __syncthreads();
    #pragma unroll
    for (int i = 0; i < 4; ++i)
        dst[(size_t)(n0 + ty + i * 8) * K + k0 + tx] = f2bf(tile[tx][ty + i * 8]);
}

// ---------------------------------------------------------------------------
// m97-style K-loop body shared by both GEMMs.
// A [*,1024] bf16 k-contig, Bt [*,1024] bf16 k-contig.
// LDS tiles 128x32 shorts unpadded; chunk swizzle col ^= (row>>1)&3 applied
// on the global-fetch side (global_load_lds LDS dest is lane-ordered).
// ---------------------------------------------------------------------------
#define GEMM_KLOOP(APTR, BPTR)                                                 \
    for (int k0 = 0; k0 < DIMM; k0 += 32) {                                    \
        _Pragma("unroll")                                                      \
        for (int j = 0; j < 2; ++j) {                                          \
            int c = j * 256 + tid;                                             \
            int r = c >> 2, jj = c & 3;                                        \
            int gc = jj ^ ((r >> 1) & 3);                                      \
            gld_lds16(APTR + (size_t)(row0 + r) * DIMM + k0 + gc * 8,          \
                      As + c * 8);                                             \
            gld_lds16(BPTR + (size_t)(col0 + r) * DIMM + k0 + gc * 8,         \
                      Bs + c * 8);                                             \
        }                                                                      \
        __syncthreads();                                                       \
        bf16x8 af[4], bfr[4];                                                  \
        _Pragma("unroll")                                                      \
        for (int mt = 0; mt < 4; ++mt) {                                       \
            int row = wm + mt * 16 + l16;                                      \
            af[mt] = lds_frag(&As[row * 32 + (quad ^ ((row >> 1) & 3)) * 8]);  \
        }                                                                      \
        _Pragma("unroll")                                                      \
        for (int nt = 0; nt < 4; ++nt) {                                       \
            int row = wn + nt * 16 + l16;                                      \
            bfr[nt] = lds_frag(&Bs[row * 32 + (quad ^ ((row >> 1) & 3)) * 8]); \
        }                                                                      \
        _Pragma("unroll")                                                      \
        for (int mt = 0; mt < 4; ++mt)                                         \
            _Pragma("unroll")                                                  \
            for (int nt = 0; nt < 4; ++nt)                                     \
                acc[mt][nt] = __builtin_amdgcn_mfma_f32_16x16x32_bf16(         \
                    af[mt], bfr[nt], acc[mt][nt], 0, 0, 0);                    \
        __syncthreads();                                                       \
    }

// ---------------------------------------------------------------------------
// GEMM1: qkv = xb[8192,1024] @ wqkvT[3072,1024]^T, scatter q/k (row) + v (T)
// ---------------------------------------------------------------------------
__global__ __launch_bounds__(256, 2)
void gemm_qkv(const short* __restrict__ a, const short* __restrict__ bt,
              short* __restrict__ qo, short* __restrict__ ko,
              short* __restrict__ vo)
{
    __shared__ short As[128 * 32];
    __shared__ short Bs[128 * 32];
    const int tid  = threadIdx.x;
    const int wave = tid >> 6, lane = tid & 63;
    const int quad = lane >> 4, l16 = lane & 15;
    const int row0 = blockIdx.x * 128, col0 = blockIdx.y * 128;
    const int wm = (wave >> 1) * 64, wn = (wave & 1) * 64;

    f32x4 acc[4][4] = {};
    GEMM_KLOOP(a, bt)

    // epilogue: scatter to q/k [BH][N][64], v [BH][64][N]
    #pragma unroll
    for (int mt = 0; mt < 4; ++mt) {
        #pragma unroll
        for (int nt = 0; nt < 4; ++nt) {
            int gcol  = col0 + wn + nt * 16 + l16;
            int which = gcol >> 10;          // 0=q 1=k 2=v
            int cc    = gcol & 1023;
            int h     = cc >> 6, d = cc & 63;
            int growb = row0 + wm + mt * 16 + quad * 4;   // rows growb..growb+3
            int b_    = growb >> 11;
            int n_    = growb & 2047;
            int bh    = b_ * NHEAD + h;
            if (which == 2) {
                short4v s = { f2bf(acc[mt][nt][0]), f2bf(acc[mt][nt][1]),
                              f2bf(acc[mt][nt][2]), f2bf(acc[mt][nt][3]) };
                *(short4v*)(vo + ((size_t)bh * HD + d) * NSEQ + n_) = s;
            } else {
                short* dst = (which == 0 ? qo : ko);
                #pragma unroll
                for (int r = 0; r < 4; ++r)
                    dst[((size_t)bh * NSEQ + n_ + r) * HD + d] = f2bf(acc[mt][nt][r]);
            }
        }
    }
}

// ---------------------------------------------------------------------------
// Flash attention (unchanged from round 1)
// ---------------------------------------------------------------------------
__global__ __launch_bounds__(256, 2)
void attn(const short* __restrict__ q, const short* __restrict__ k,
          const short* __restrict__ vt, short* __restrict__ o)
{
    __shared__ short Qs[64][72];
    __shared__ short Ks[128][72];
    __shared__ short Vts[64][136];
    __shared__ short Ps[64][136];

    const int tid  = threadIdx.x;
    const int wave = tid >> 6, lane = tid & 63;
    const int quad = lane >> 4, l16 = lane & 15;
    const int bh   = blockIdx.y;
    const int q0   = blockIdx.x * 64;
    const size_t qkbase = (size_t)bh * NSEQ * HD;
    const size_t vbase  = (size_t)bh * HD * NSEQ;

    #pragma unroll
    for (int i = 0; i < 2; ++i) {
        int f = tid + i * 256;
        int r = f >> 3, dg = (f & 7) * 8;
        *(short8*)&Qs[r][dg] = *(const short8*)(q + qkbase + (size_t)(q0 + r) * HD + dg);
    }
    __syncthreads();

    bf16x8 qf[2];
    #pragma unroll
    for (int ks = 0; ks < 2; ++ks)
        qf[ks] = lds_frag(&Qs[wave * 16 + l16][ks * 32 + quad * 8]);

    f32x4 oacc[4] = {};
    float mst[4], lst[4];
    #pragma unroll
    for (int r = 0; r < 4; ++r) { mst[r] = -1e30f; lst[r] = 0.f; }

    for (int kv0 = 0; kv0 < NSEQ; kv0 += 128) {
        #pragma unroll
        for (int i = 0; i < 4; ++i) {
            int f = tid + i * 256;
            int r = f >> 3, dg = (f & 7) * 8;
            *(short8*)&Ks[r][dg] = *(const short8*)(k + qkbase + (size_t)(kv0 + r) * HD + dg);
        }
        #pragma unroll
        for (int i = 0; i < 4; ++i) {
            int f = tid + i * 256;
            int r = f >> 4, jg = (f & 15) * 8;
            *(short8*)&Vts[r][jg] = *(const short8*)(vt + vbase + (size_t)r * NSEQ + kv0 + jg);
        }
        __syncthreads();

        f32x4 sacc[8] = {};
        #pragma unroll
        for (int ks = 0; ks < 2; ++ks) {
            #pragma unroll
            for (int nt = 0; nt < 8; ++nt) {
                bf16x8 kf = lds_frag(&Ks[nt * 16 + l16][ks * 32 + quad * 8]);
                sacc[nt] = __builtin_amdgcn_mfma_f32_16x16x32_bf16(qf[ks], kf, sacc[nt], 0, 0, 0);
            }
        }

        #pragma unroll
        for (int r = 0; r < 4; ++r) {
            float rmax = -1e30f;
            #pragma unroll
            for (int nt = 0; nt < 8; ++nt) rmax = fmaxf(rmax, sacc[nt][r]);
            rmax *= SCALE;
            #pragma unroll
            for (int off = 1; off < 16; off <<= 1)
                rmax = fmaxf(rmax, __shfl_xor(rmax, off));
            float mnew  = fmaxf(mst[r], rmax);
            float alpha = __expf(mst[r] - mnew);
            float rsum  = 0.f;
            int prow = wave * 16 + quad * 4 + r;
            #pragma unroll
            for (int nt = 0; nt < 8; ++nt) {
                float p = __expf(sacc[nt][r] * SCALE - mnew);
                Ps[prow][nt * 16 + l16] = f2bf(p);
                rsum += p;
            }
            #pragma unroll
            for (int off = 1; off < 16; off <<= 1)
                rsum += __shfl_xor(rsum, off);
            lst[r] = lst[r] * alpha + rsum;
            mst[r] = mnew;
            #pragma unroll
            for (int ot = 0; ot < 4; ++ot) oacc[ot][r] *= alpha;
        }

        #pragma unroll
        for (int ks = 0; ks < 4; ++ks) {
            bf16x8 pf = lds_frag(&Ps[wave * 16 + l16][ks * 32 + quad * 8]);
            #pragma unroll
            for (int ot = 0; ot < 4; ++ot) {
                bf16x8 vf = lds_frag(&Vts[ot * 16 + l16][ks * 32 + quad * 8]);
                oacc[ot] = __builtin_amdgcn_mfma_f32_16x16x32_bf16(pf, vf, oacc[ot], 0, 0, 0);
            }
        }
        __syncthreads();
    }

    const int b_ = bh >> 4, h = bh & 15;
    #pragma unroll
    for (int ot = 0; ot < 4; ++ot) {
        #pragma unroll
        for (int r = 0; r < 4; ++r) {
            int row = q0 + wave * 16 + quad * 4 + r;
            int d   = ot * 16 + l16;
            float val = oacc[ot][r] / lst[r];
            o[((size_t)b_ * NSEQ + row) * DIMM + h * HD + d] = f2bf(val);
        }
    }
}

// ---------------------------------------------------------------------------
// GEMM2: out = ob[8192,1024](bf16) @ woutT[1024,1024]^T + b_out, fp32 out
// ---------------------------------------------------------------------------
__global__ __launch_bounds__(256, 2)
void gemm_out(const short* __restrict__ a, const short* __restrict__ bt,
              const float* __restrict__ bias, float* __restrict__ out)
{
    __shared__ short As[128 * 32];
    __shared__ short Bs[128 * 32];
    const int tid  = threadIdx.x;
    const int wave = tid >> 6, lane = tid & 63;
    const int quad = lane >> 4, l16 = lane & 15;
    const int row0 = blockIdx.x * 128, col0 = blockIdx.y * 128;
    const int wm = (wave >> 1) * 64, wn = (wave & 1) * 64;

    f32x4 acc[4][4] = {};
    GEMM_KLOOP(a, bt)

    #pragma unroll
    for (int mt = 0; mt < 4; ++mt) {
        #pragma unroll
        for (int nt = 0; nt < 4; ++nt) {
            int gcol = col0 + wn + nt * 16 + l16;
            float bb = bias[gcol];
            #pragma unroll
            for (int r = 0; r < 4; ++r) {
                int grow = row0 + wm + mt * 16 + quad * 4 + r;
                out[(size_t)grow * DIMM + gcol] = acc[mt][nt][r] + bb;
            }
        }
    }
}

// ---------------------------------------------------------------------------
extern "C" void kernel_launch(void* const* d_in, const int* in_sizes, int n_in,
                              void* d_out, int out_size, void* d_ws, size_t ws_size,
                              hipStream_t stream)
{
    const float* x     = (const float*)d_in[0];
    const float* w_qkv = (const float*)d_in[1];
    const float* w_out = (const float*)d_in[2];
    const float* b_out = (const float*)d_in[3];
    float* out = (float*)d_out;

    const size_t per = (size_t)BSZ * NHEAD * NSEQ * HD;  // 8.39M elems
    short* q     = (short*)d_ws;
    short* kk    = q  + per;
    short* v     = kk + per;
    short* xb_ob = v  + per;              // x-bf16, later aliased as attn out
    short* wqkvT = xb_ob + per;           // [3072][1024]
    short* woutT = wqkvT + (size_t)N3 * DIMM;  // [1024][1024]

    cvt_bf16<<<(int)(per / 8 / 256), 256, 0, stream>>>(x, xb_ob, (int)(per / 8));
    transpose_bf16<<<dim3(N3 / 32, DIMM / 32), dim3(32, 8), 0, stream>>>(w_qkv, wqkvT, DIMM, N3);
    transpose_bf16<<<dim3(DIMM / 32, DIMM / 32), dim3(32, 8), 0, stream>>>(w_out, woutT, DIMM, DIMM);

    gemm_qkv<<<dim3(MTOK / 128, N3 / 128), 256, 0, stream>>>(xb_ob, wqkvT, q, kk, v);
    attn<<<dim3(NSEQ / 64, BSZ * NHEAD), 256, 0, stream>>>(q, kk, v, xb_ob);
    gemm_out<<<dim3(MTOK / 128, DIMM / 128), 256, 0, stream>>>(xb_ob, woutT, b_out, out);
}